// Round 1
// baseline (115.011 us; speedup 1.0000x reference)
//
#include <hip/hip_runtime.h>
#include <math.h>

#define TAG_O 1

struct Accum {
  double conf_sum;
  double cls_sum;
  double reg_sum;
  unsigned int cls_cnt;
  unsigned int pos_cnt;
  unsigned int pad0, pad1;
};

__device__ __forceinline__ float waveReduce(float v) {
#pragma unroll
  for (int off = 32; off > 0; off >>= 1) v += __shfl_down(v, off, 64);
  return v;
}
__device__ __forceinline__ unsigned waveReduceU(unsigned v) {
#pragma unroll
  for (int off = 32; off > 0; off >>= 1) v += __shfl_down(v, off, 64);
  return v;
}

// One thread per (b,s,a). Each block handles 256 consecutive (s,a) slots of a
// single batch b, so entity compaction (index[e]==b) is done once per block.
__global__ __launch_bounds__(256) void ssd_main(
    const int* __restrict__ input_len,
    const float* __restrict__ conf_logits,
    const float* __restrict__ cls_logits,
    const float* __restrict__ reg_logits,
    const float* __restrict__ label,      // (E,3): type, ll, lr
    const int* __restrict__ index,        // (E,)
    const float* __restrict__ anchors,    // (S,A,2): center, size
    const float* __restrict__ thr_pos_p,
    const float* __restrict__ thr_neg_p,
    Accum* __restrict__ acc,
    int S, int A, int L, int E, int blocksPerB)
{
  __shared__ float4 ents[1024];  // x=ll, y=lr, z=type, w=orig index (bits)
  __shared__ int entCnt;
  __shared__ float s_conf[4], s_cls[4], s_reg[4];
  __shared__ unsigned s_cc[4], s_pc[4];

  const int tid = threadIdx.x;
  const int b = blockIdx.x / blocksPerB;
  const int rel = (blockIdx.x % blocksPerB) * blockDim.x + tid; // (s*A + a)
  const int s = rel / A;
  const int SA = S * A;
  const size_t gid = (size_t)b * SA + rel;

  if (tid == 0) entCnt = 0;
  __syncthreads();
  for (int e = tid; e < E; e += blockDim.x) {
    if (index[e] == b) {
      int p = atomicAdd(&entCnt, 1);
      if (p < 1024) {
        ents[p] = make_float4(label[3 * e + 1], label[3 * e + 2],
                              label[3 * e + 0], __int_as_float(e));
      }
    }
  }
  __syncthreads();
  const int nE = min(entCnt, 1024);

  const float ac  = anchors[(size_t)rel * 2 + 0];
  const float asz = anchors[(size_t)rel * 2 + 1];
  const float al = ac - asz * 0.5f;   // matches ref: ac - asz/2.0
  const float ar = ac + asz * 0.5f;

  // max-IoU + first-occurrence argmax (tie-break on original entity index,
  // because LDS compaction order is nondeterministic).
  float best = -1.0f;
  int bestOrig = 0x7fffffff;
  float bLl = 0.f, bLr = 0.f, bTy = 0.f;
  for (int i = 0; i < nE; ++i) {
    float4 en = ents[i];
    // exact reference op order for bit-identical threshold decisions:
    float inter = fminf(en.y, ar) - fmaxf(en.x, al);
    inter = fmaxf(inter, 0.0f);
    float uni = (en.y - en.x) + (ar - al) - inter;
    float iou = inter / uni;
    int oi = __float_as_int(en.w);
    if (iou > best || (iou == best && oi < bestOrig)) {
      best = iou; bestOrig = oi;
      bLl = en.x; bLr = en.y; bTy = en.z;
    }
  }

  const int len = input_len[b];
  const bool active = (s < len) && (nE > 0);
  const float thrP = *thr_pos_p;
  const float thrN = *thr_neg_p;
  const bool pos = active && (best >= thrP);
  const bool neg = active && (best <= thrN);

  // ---- conf: softplus(x) - x*conf_lab, mean over ALL B*S*A ----
  float x = conf_logits[gid];
  float confc = fmaxf(x, 0.0f) + log1pf(expf(-fabsf(x)));
  if (pos) confc -= x;

  // ---- cls: NLL at target where pos|neg ----
  float clsc = 0.0f;
  unsigned cc = 0;
  if (pos || neg) {
    const int target = pos ? (int)bTy : TAG_O;
    const float* row = cls_logits + gid * (size_t)L;
    float mx = -INFINITY;
    int L4 = L >> 2;
    const float4* row4 = (const float4*)row;
    for (int i = 0; i < L4; ++i) {
      float4 v = row4[i];
      mx = fmaxf(mx, fmaxf(fmaxf(v.x, v.y), fmaxf(v.z, v.w)));
    }
    for (int i = L4 << 2; i < L; ++i) mx = fmaxf(mx, row[i]);
    float sum = 0.0f;
    for (int i = 0; i < L4; ++i) {
      float4 v = row4[i];
      sum += expf(v.x - mx) + expf(v.y - mx) + expf(v.z - mx) + expf(v.w - mx);
    }
    for (int i = L4 << 2; i < L; ++i) sum += expf(row[i] - mx);
    clsc = logf(sum) + mx - row[target];
    cc = 1;
  }

  // ---- reg: SE at pos anchors ----
  float regc = 0.0f;
  unsigned pc = 0;
  if (pos) {
    float lc = (bLl + bLr) * 0.5f;
    float ls = bLr - bLl;
    float offc = (lc - ac) / asz;
    float offs = ls / asz;
    float r0 = reg_logits[gid * 2 + 0] - offc;
    float r1 = reg_logits[gid * 2 + 1] - offs;
    regc = r0 * r0 + r1 * r1;
    pc = 1;
  }

  // ---- block reduction ----
  const int wave = tid >> 6, lane = tid & 63;
  confc = waveReduce(confc);
  clsc = waveReduce(clsc);
  regc = waveReduce(regc);
  cc = waveReduceU(cc);
  pc = waveReduceU(pc);
  if (lane == 0) {
    s_conf[wave] = confc; s_cls[wave] = clsc; s_reg[wave] = regc;
    s_cc[wave] = cc; s_pc[wave] = pc;
  }
  __syncthreads();
  if (tid == 0) {
    float cs = s_conf[0] + s_conf[1] + s_conf[2] + s_conf[3];
    float ls_ = s_cls[0] + s_cls[1] + s_cls[2] + s_cls[3];
    float rs = s_reg[0] + s_reg[1] + s_reg[2] + s_reg[3];
    unsigned ccs = s_cc[0] + s_cc[1] + s_cc[2] + s_cc[3];
    unsigned pcs = s_pc[0] + s_pc[1] + s_pc[2] + s_pc[3];
    atomicAdd(&acc->conf_sum, (double)cs);
    atomicAdd(&acc->cls_sum, (double)ls_);
    atomicAdd(&acc->reg_sum, (double)rs);
    atomicAdd(&acc->cls_cnt, ccs);
    atomicAdd(&acc->pos_cnt, pcs);
  }
}

__global__ void ssd_final(const Accum* __restrict__ acc,
                          float* __restrict__ out, int totalN) {
  float cf = (float)(acc->conf_sum / (double)totalN);
  float cl = (float)(acc->cls_sum / (double)acc->cls_cnt);
  float rg = (float)(acc->reg_sum / (2.0 * (double)acc->pos_cnt));
  out[0] = cf + cl + rg;  // W_CONF = W_CLS = W_REG = 1
  out[1] = cf;
  out[2] = cl;
  out[3] = rg;
}

extern "C" void kernel_launch(void* const* d_in, const int* in_sizes, int n_in,
                              void* d_out, int out_size, void* d_ws,
                              size_t ws_size, hipStream_t stream) {
  const int*   input_len   = (const int*)  d_in[0];
  const float* conf_logits = (const float*)d_in[1];
  const float* cls_logits  = (const float*)d_in[2];
  const float* reg_logits  = (const float*)d_in[3];
  const float* label       = (const float*)d_in[4];
  const int*   index       = (const int*)  d_in[5];
  const float* anchors     = (const float*)d_in[6];
  const float* thr_pos     = (const float*)d_in[7];
  const float* thr_neg     = (const float*)d_in[8];

  const int B   = in_sizes[0];
  const int BSA = in_sizes[1];
  const int L   = in_sizes[2] / BSA;      // 32
  const int E   = in_sizes[5];            // 256
  const int SA  = BSA / B;                // 4096
  const int A   = 8;                      // anchor_sizes has 8 entries
  const int S   = SA / A;                 // 512

  Accum* acc = (Accum*)d_ws;
  hipMemsetAsync(acc, 0, sizeof(Accum), stream);

  const int threads = 256;
  const int blocksPerB = SA / threads;    // 16
  dim3 grid(B * blocksPerB);              // 512 blocks
  hipLaunchKernelGGL(ssd_main, grid, dim3(threads), 0, stream,
                     input_len, conf_logits, cls_logits, reg_logits, label,
                     index, anchors, thr_pos, thr_neg, acc,
                     S, A, L, E, blocksPerB);
  hipLaunchKernelGGL(ssd_final, dim3(1), dim3(1), 0, stream,
                     acc, (float*)d_out, BSA);
}

// Round 2
// 90.458 us; speedup vs baseline: 1.2714x; 1.2714x over previous
//
#include <hip/hip_runtime.h>
#include <math.h>

#define TAG_O 1

// Per-block partial slot (32 B, two float4): written unconditionally by every
// block, so no zero-init of d_ws is needed (harness poisons it to 0xAA).
//   [0]=conf_sum [1]=cls_sum [2]=reg_sum [3]=cls_cnt [4]=pos_cnt [5..7]=0

__device__ __forceinline__ float waveReduce(float v) {
#pragma unroll
  for (int off = 32; off > 0; off >>= 1) v += __shfl_down(v, off, 64);
  return v;
}

// One thread per (b,s,a). Each block handles 256 consecutive (s,a) slots of a
// single batch b, so entity compaction (index[e]==b) is done once per block.
__global__ __launch_bounds__(256) void ssd_main(
    const int* __restrict__ input_len,
    const float* __restrict__ conf_logits,
    const float* __restrict__ cls_logits,
    const float* __restrict__ reg_logits,
    const float* __restrict__ label,      // (E,3): type, ll, lr
    const int* __restrict__ index,        // (E,)
    const float* __restrict__ anchors,    // (S,A,2): center, size
    const float* __restrict__ thr_pos_p,
    const float* __restrict__ thr_neg_p,
    float* __restrict__ partials,         // (grid, 8)
    int S, int A, int L, int E, int blocksPerB)
{
  __shared__ float4 ents[1024];  // x=ll, y=lr, z=type, w=orig index (bits)
  __shared__ int entCnt;
  __shared__ float s_red[4][5];

  const int tid = threadIdx.x;
  const int b = blockIdx.x / blocksPerB;
  const int rel = (blockIdx.x % blocksPerB) * blockDim.x + tid; // (s*A + a)
  const int s = rel / A;
  const int SA = S * A;
  const size_t gid = (size_t)b * SA + rel;

  if (tid == 0) entCnt = 0;
  __syncthreads();
  for (int e = tid; e < E; e += blockDim.x) {
    if (index[e] == b) {
      int p = atomicAdd(&entCnt, 1);
      if (p < 1024) {
        ents[p] = make_float4(label[3 * e + 1], label[3 * e + 2],
                              label[3 * e + 0], __int_as_float(e));
      }
    }
  }
  __syncthreads();
  const int nE = min(entCnt, 1024);

  const float ac  = anchors[(size_t)rel * 2 + 0];
  const float asz = anchors[(size_t)rel * 2 + 1];
  const float al = ac - asz * 0.5f;   // matches ref: ac - asz/2.0
  const float ar = ac + asz * 0.5f;

  // max-IoU + first-occurrence argmax (tie-break on original entity index,
  // because LDS compaction order is nondeterministic).
  float best = -1.0f;
  int bestOrig = 0x7fffffff;
  float bLl = 0.f, bLr = 0.f, bTy = 0.f;
  for (int i = 0; i < nE; ++i) {
    float4 en = ents[i];
    // exact reference op order for bit-identical threshold decisions:
    float inter = fminf(en.y, ar) - fmaxf(en.x, al);
    inter = fmaxf(inter, 0.0f);
    float uni = (en.y - en.x) + (ar - al) - inter;
    float iou = inter / uni;
    int oi = __float_as_int(en.w);
    if (iou > best || (iou == best && oi < bestOrig)) {
      best = iou; bestOrig = oi;
      bLl = en.x; bLr = en.y; bTy = en.z;
    }
  }

  const int len = input_len[b];
  const bool active = (s < len) && (nE > 0);
  const float thrP = *thr_pos_p;
  const float thrN = *thr_neg_p;
  const bool pos = active && (best >= thrP);
  const bool neg = active && (best <= thrN);

  // ---- conf: softplus(x) - x*conf_lab, mean over ALL B*S*A ----
  float x = conf_logits[gid];
  float confc = fmaxf(x, 0.0f) + log1pf(__expf(-fabsf(x)));
  if (pos) confc -= x;

  // ---- cls: NLL at target where pos|neg ----
  float clsc = 0.0f;
  float cc = 0.0f;
  if (pos || neg) {
    const int target = pos ? (int)bTy : TAG_O;
    const float* row = cls_logits + gid * (size_t)L;
    const float4* row4 = (const float4*)row;
    float mx = -INFINITY;
    const int L4 = L >> 2;
#pragma unroll 8
    for (int i = 0; i < L4; ++i) {
      float4 v = row4[i];
      mx = fmaxf(mx, fmaxf(fmaxf(v.x, v.y), fmaxf(v.z, v.w)));
    }
    float sum = 0.0f;
#pragma unroll 8
    for (int i = 0; i < L4; ++i) {
      float4 v = row4[i];
      sum += __expf(v.x - mx) + __expf(v.y - mx) +
             __expf(v.z - mx) + __expf(v.w - mx);
    }
    clsc = __logf(sum) + mx - row[target];
    cc = 1.0f;
  }

  // ---- reg: SE at pos anchors ----
  float regc = 0.0f;
  float pc = 0.0f;
  if (pos) {
    float lc = (bLl + bLr) * 0.5f;
    float ls = bLr - bLl;
    float offc = (lc - ac) / asz;
    float offs = ls / asz;
    float r0 = reg_logits[gid * 2 + 0] - offc;
    float r1 = reg_logits[gid * 2 + 1] - offs;
    regc = r0 * r0 + r1 * r1;
    pc = 1.0f;
  }

  // ---- block reduction → one 32 B partial slot ----
  const int wave = tid >> 6, lane = tid & 63;
  confc = waveReduce(confc);
  clsc = waveReduce(clsc);
  regc = waveReduce(regc);
  cc = waveReduce(cc);
  pc = waveReduce(pc);
  if (lane == 0) {
    s_red[wave][0] = confc; s_red[wave][1] = clsc; s_red[wave][2] = regc;
    s_red[wave][3] = cc;    s_red[wave][4] = pc;
  }
  __syncthreads();
  if (tid == 0) {
    float4 lo = make_float4(
        s_red[0][0] + s_red[1][0] + s_red[2][0] + s_red[3][0],
        s_red[0][1] + s_red[1][1] + s_red[2][1] + s_red[3][1],
        s_red[0][2] + s_red[1][2] + s_red[2][2] + s_red[3][2],
        s_red[0][3] + s_red[1][3] + s_red[2][3] + s_red[3][3]);
    float4 hi = make_float4(
        s_red[0][4] + s_red[1][4] + s_red[2][4] + s_red[3][4], 0.f, 0.f, 0.f);
    float4* slot = (float4*)(partials + (size_t)blockIdx.x * 8);
    slot[0] = lo;
    slot[1] = hi;
  }
}

// Reduce nSlots 8-float partials and emit the 4 outputs. One block.
__global__ __launch_bounds__(256) void ssd_final(
    const float* __restrict__ partials, float* __restrict__ out,
    int nSlots, int totalN) {
  __shared__ float s_red[4][5];
  const int tid = threadIdx.x;
  float v0 = 0.f, v1 = 0.f, v2 = 0.f, v3 = 0.f, v4 = 0.f;
  for (int i = tid; i < nSlots; i += blockDim.x) {
    const float4* slot = (const float4*)(partials + (size_t)i * 8);
    float4 lo = slot[0];
    float4 hi = slot[1];
    v0 += lo.x; v1 += lo.y; v2 += lo.z; v3 += lo.w; v4 += hi.x;
  }
  const int wave = tid >> 6, lane = tid & 63;
  v0 = waveReduce(v0); v1 = waveReduce(v1); v2 = waveReduce(v2);
  v3 = waveReduce(v3); v4 = waveReduce(v4);
  if (lane == 0) {
    s_red[wave][0] = v0; s_red[wave][1] = v1; s_red[wave][2] = v2;
    s_red[wave][3] = v3; s_red[wave][4] = v4;
  }
  __syncthreads();
  if (tid == 0) {
    double conf_sum = (double)(s_red[0][0] + s_red[1][0] + s_red[2][0] + s_red[3][0]);
    double cls_sum  = (double)(s_red[0][1] + s_red[1][1] + s_red[2][1] + s_red[3][1]);
    double reg_sum  = (double)(s_red[0][2] + s_red[1][2] + s_red[2][2] + s_red[3][2]);
    double cls_cnt  = (double)(s_red[0][3] + s_red[1][3] + s_red[2][3] + s_red[3][3]);
    double pos_cnt  = (double)(s_red[0][4] + s_red[1][4] + s_red[2][4] + s_red[3][4]);
    float cf = (float)(conf_sum / (double)totalN);
    float cl = (float)(cls_sum / cls_cnt);
    float rg = (float)(reg_sum / (2.0 * pos_cnt));
    out[0] = cf + cl + rg;  // W_CONF = W_CLS = W_REG = 1
    out[1] = cf;
    out[2] = cl;
    out[3] = rg;
  }
}

extern "C" void kernel_launch(void* const* d_in, const int* in_sizes, int n_in,
                              void* d_out, int out_size, void* d_ws,
                              size_t ws_size, hipStream_t stream) {
  const int*   input_len   = (const int*)  d_in[0];
  const float* conf_logits = (const float*)d_in[1];
  const float* cls_logits  = (const float*)d_in[2];
  const float* reg_logits  = (const float*)d_in[3];
  const float* label       = (const float*)d_in[4];
  const int*   index       = (const int*)  d_in[5];
  const float* anchors     = (const float*)d_in[6];
  const float* thr_pos     = (const float*)d_in[7];
  const float* thr_neg     = (const float*)d_in[8];

  const int B   = in_sizes[0];
  const int BSA = in_sizes[1];
  const int L   = in_sizes[2] / BSA;      // 32
  const int E   = in_sizes[5];            // 256
  const int SA  = BSA / B;                // 4096
  const int A   = 8;                      // anchor_sizes has 8 entries
  const int S   = SA / A;                 // 512

  float* partials = (float*)d_ws;

  const int threads = 256;
  const int blocksPerB = SA / threads;    // 16
  const int nBlocks = B * blocksPerB;     // 512
  hipLaunchKernelGGL(ssd_main, dim3(nBlocks), dim3(threads), 0, stream,
                     input_len, conf_logits, cls_logits, reg_logits, label,
                     index, anchors, thr_pos, thr_neg, partials,
                     S, A, L, E, blocksPerB);
  hipLaunchKernelGGL(ssd_final, dim3(1), dim3(threads), 0, stream,
                     partials, (float*)d_out, nBlocks, BSA);
}